// Round 7
// baseline (548.312 us; speedup 1.0000x reference)
//
#include <hip/hip_runtime.h>
#include <hip/hip_bf16.h>
#include <hip/hip_cooperative_groups.h>

namespace cg = cooperative_groups;

#define B_ 128
#define T_ 512
#define N_ 256
#define H_ 1024

typedef unsigned short u16;
typedef __attribute__((ext_vector_type(8))) __bf16 bf16x8;
typedef __attribute__((ext_vector_type(4))) float f32x4;

__device__ __forceinline__ u16 f2bf(float f) {
    unsigned u = __float_as_uint(f);
    u = (u + 0x7FFFu + ((u >> 16) & 1u)) >> 16;
    return (u16)u;
}

__device__ __forceinline__ void g2l16(const void* g, void* l) {
    __builtin_amdgcn_global_load_lds(
        (const __attribute__((address_space(1))) void*)g,
        (__attribute__((address_space(3))) void*)l,
        16, 0, 0);
}

// ===========================================================================
// 256x256-tile 8-wave phase-pipelined GEMM body (device fn), R6 schedule.
// R7: all three main GEMMs run inside ONE cooperative persistent kernel.
// OUT: 0 = bf16 row-major, 1 = f32 row-major, 2 = bf16 transposed q-write.
// ===========================================================================
#define LBUF 32768u
#define LMAT 16384u
#define LKS  8192u

#define BAR() { __builtin_amdgcn_s_barrier(); }
#define GATE(N) { asm volatile("s_waitcnt vmcnt(" #N ")" ::: "memory"); \
                  __builtin_amdgcn_s_barrier(); }
#define LD4(dst, base) { _Pragma("unroll") for (int i_ = 0; i_ < 4; ++i_) \
    dst[i_] = *(const bf16x8*)(L + (base) + i_ * 512); }
#define MF16(MB, RA, RB) { __builtin_amdgcn_s_setprio(1); \
    _Pragma("unroll") for (int mi_ = 0; mi_ < 4; ++mi_) \
    _Pragma("unroll") for (int ni_ = 0; ni_ < 4; ++ni_) \
        acc[(MB) + mi_][ni_] = __builtin_amdgcn_mfma_f32_16x16x32_bf16( \
            RA[mi_], RB[ni_], acc[(MB) + mi_][ni_], 0, 0, 0); \
    __builtin_amdgcn_s_setprio(0); }

template<int ACT, int OUT>
__device__ __forceinline__ void g256_body(
    u16* __restrict__ L,
    const u16* __restrict__ A, const u16* __restrict__ Bt,
    float* __restrict__ Cf, u16* __restrict__ Cb,
    const float* __restrict__ bias,
    int Nc, int K, int bshift, int gysh, int orig, int nwg)
{
    // drain previous body's epilogue stores so GATE counts see only our loads
    asm volatile("s_waitcnt vmcnt(0)" ::: "memory");

    const int tid = threadIdx.x;
    const int wave = tid >> 6, lane = tid & 63;
    const int l16 = lane & 15, lh = lane >> 4;
    const int wm = wave >> 2, wn = wave & 3;

    const int qq = nwg >> 3;
    const int wg = (orig & 7) * qq + (orig >> 3);
    const int by = wg & ((1 << gysh) - 1), bx = wg >> gysh;
    const size_t m0 = (size_t)bx * 256, n0 = (size_t)by * 256;

    const int sx8 = (lh ^ ((l16 >> 1) & 3)) * 8;
    const unsigned aoff = (unsigned)(wm * 4096 + l16 * 32 + sx8);
    const unsigned boff = (unsigned)(LMAT + wn * 2048 + l16 * 32 + sx8);

    const int srow = tid >> 2;
    const int sslot = (tid & 3) ^ ((srow >> 1) & 3);
    const size_t jstr = (size_t)128 * K;
    const u16* gA = A + (m0 + srow) * (size_t)K + sslot * 8;
    const u16* gB = Bt + (n0 + srow) * (size_t)K + sslot * 8;
    u16* const dA0 = L + (unsigned)(wave * 512);
    u16* const dB0 = L + LMAT + (unsigned)(wave * 512);

    f32x4 acc[8][4] = {};
    const int nt = K >> 6;

    g2l16(gA, dA0);             g2l16(gA + jstr, dA0 + 4096);
    g2l16(gB, dB0);             g2l16(gB + jstr, dB0 + 4096);
    g2l16(gA + 32, dA0 + LKS);  g2l16(gA + 32 + jstr, dA0 + LKS + 4096);
    g2l16(gB + 32, dB0 + LKS);  g2l16(gB + 32 + jstr, dB0 + LKS + 4096);
    GATE(4);

    for (int t = 0; t < nt - 1; ++t) {
        const unsigned ab = (t & 1) ? LBUF : 0u;
        const unsigned an = ab ^ LBUF;
        const u16* gAt = gA + (size_t)(t + 1) * 64;
        const u16* gBt = gB + (size_t)(t + 1) * 64;
        bf16x8 ra[4], ra2[4], rb0r[4], rb1r[4];
        LD4(ra,   ab + aoff);
        LD4(rb0r, ab + boff);
        g2l16(gAt, dA0 + an);  g2l16(gAt + jstr, dA0 + an + 4096);
        BAR();
        MF16(0, ra, rb0r);
        BAR();
        LD4(ra2, ab + aoff + 2048);
        g2l16(gBt, dB0 + an);  g2l16(gBt + jstr, dB0 + an + 4096);
        BAR();
        MF16(4, ra2, rb0r);
        GATE(4);
        LD4(ra,   ab + LKS + aoff);
        LD4(rb1r, ab + LKS + boff);
        g2l16(gAt + 32, dA0 + an + LKS);  g2l16(gAt + 32 + jstr, dA0 + an + LKS + 4096);
        BAR();
        MF16(0, ra, rb1r);
        BAR();
        LD4(ra2, ab + LKS + aoff + 2048);
        g2l16(gBt + 32, dB0 + an + LKS);  g2l16(gBt + 32 + jstr, dB0 + an + LKS + 4096);
        BAR();
        MF16(4, ra2, rb1r);
        GATE(4);
    }

    {
        const unsigned ab = ((nt - 1) & 1) ? LBUF : 0u;
        bf16x8 ra[4], ra2[4], rb0r[4], rb1r[4];
        LD4(ra,   ab + aoff);
        LD4(rb0r, ab + boff);
        BAR();
        MF16(0, ra, rb0r);
        BAR();
        LD4(ra2, ab + aoff + 2048);
        BAR();
        MF16(4, ra2, rb0r);
        GATE(0);
        LD4(ra,   ab + LKS + aoff);
        LD4(rb1r, ab + LKS + boff);
        BAR();
        MF16(0, ra, rb1r);
        BAR();
        LD4(ra2, ab + LKS + aoff + 2048);
        BAR();
        MF16(4, ra2, rb1r);
    }

    const size_t NcS = (size_t)Nc;
#pragma unroll
    for (int mi = 0; mi < 8; ++mi) {
#pragma unroll
        for (int ni = 0; ni < 4; ++ni) {
            size_t rbase = m0 + wm * 128 + mi * 16 + lh * 4;
            size_t col   = n0 + wn * 64 + ni * 16 + l16;
            if (OUT == 2) {
                u16 e[4];
#pragma unroll
                for (int rr = 0; rr < 4; ++rr) {
                    float v = acc[mi][ni][rr];
                    v = 1.0f / (1.0f + __expf(-v));
                    e[rr] = f2bf(v);
                }
                size_t qi = ((rbase >> 8) * (size_t)T_ + col) * N_ + (rbase & 255);
                *(uint2*)(Cb + qi) = *(const uint2*)e;
            } else {
#pragma unroll
                for (int rr = 0; rr < 4; ++rr) {
                    size_t row = rbase + rr;
                    float v = acc[mi][ni][rr];
                    if (bias) v += bias[(row >> bshift) * NcS + col];
                    if (ACT) v = 1.0f / (1.0f + __expf(-v));
                    if (OUT == 1) Cf[row * NcS + col] = v;
                    else          Cb[row * NcS + col] = f2bf(v);
                }
            }
        }
    }
}

// Persistent cooperative kernel: GA -> sync -> GB -> sync -> GC.
__global__ __launch_bounds__(512, 2) void mega(
    const u16* __restrict__ h_bf, const u16* __restrict__ W12t,
    const float* __restrict__ t12, u16* __restrict__ h2_bf,
    const u16* __restrict__ W1ct, u16* __restrict__ q_bf,
    const u16* __restrict__ W2ct, float* __restrict__ out)
{
    __shared__ u16 L[65536];
    cg::grid_group grid = cg::this_grid();
    const int bid = (int)blockIdx.x;

    // GA: h2 = h @ W12 + t12   [32768,1024] K=512, 512 tiles
    for (int i = bid; i < 512; i += 256)
        g256_body<0, 0>(L, h_bf, W12t, nullptr, h2_bf, t12, 1024, 512, 8, 2, i, 512);
    __threadfence();
    grid.sync();

    // GB: q = sigma(h2 @ W1c), transposed q[B,T,N]   K=1024, 256 tiles
    g256_body<1, 2>(L, h2_bf, W1ct, nullptr, q_bf, nullptr, 512, 1024, 0, 1, bid, 256);
    __threadfence();
    grid.sync();

    // GC: out = sigma(q @ W2c) f32   [65536,1024] K=256, 1024 tiles
    for (int i = bid; i < 1024; i += 256)
        g256_body<1, 1>(L, q_bf, W2ct, out, nullptr, nullptr, 1024, 256, 0, 2, i, 1024);
}

// ---------------------------------------------------------------------------
// 128x128 2-barrier GEMM body (device fn) for small GEMMs.
// ---------------------------------------------------------------------------
__device__ __forceinline__ void small_body(
    const u16* __restrict__ A, const u16* __restrict__ Bt,
    float* __restrict__ Cf, u16* __restrict__ Cb,
    const float* __restrict__ bias,
    int Nc, int K, int lda, int ldb, int outmode, int bshift,
    float kscale, float bmul, int bx, int by)
{
    __shared__ u16 lA[128 * 64];
    __shared__ u16 lB[128 * 64];
    const int tid = threadIdx.x;
    const int wave = tid >> 6, lane = tid & 63;
    const int l16 = lane & 15, lh = lane >> 4;
    const int wm = wave >> 1, wn = wave & 1;
    const long m0 = (long)bx * 128;
    const long n0 = (long)by * 128;

    f32x4 acc[4][4] = {};

    for (int k0 = 0; k0 < K; k0 += 64) {
#pragma unroll
        for (int j = 0; j < 4; ++j) {
            int c = j * 256 + tid;
            int row = c >> 3, col = (c & 7) << 3;
            g2l16(A  + (m0 + row) * (size_t)lda + k0 + col, &lA[(size_t)(j * 256 + (wave << 6)) * 8]);
            g2l16(Bt + (n0 + row) * (size_t)ldb + k0 + col, &lB[(size_t)(j * 256 + (wave << 6)) * 8]);
        }
        __syncthreads();
#pragma unroll
        for (int s = 0; s < 2; ++s) {
            bf16x8 af[4], bfr[4];
#pragma unroll
            for (int mi = 0; mi < 4; ++mi)
                af[mi] = *(const bf16x8*)&lA[((wm << 6) + (mi << 4) + l16) * 64 + s * 32 + (lh << 3)];
#pragma unroll
            for (int ni = 0; ni < 4; ++ni)
                bfr[ni] = *(const bf16x8*)&lB[((wn << 6) + (ni << 4) + l16) * 64 + s * 32 + (lh << 3)];
#pragma unroll
            for (int mi = 0; mi < 4; ++mi)
#pragma unroll
                for (int ni = 0; ni < 4; ++ni)
                    acc[mi][ni] = __builtin_amdgcn_mfma_f32_16x16x32_bf16(af[mi], bfr[ni], acc[mi][ni], 0, 0, 0);
        }
        __syncthreads();
    }

#pragma unroll
    for (int mi = 0; mi < 4; ++mi) {
#pragma unroll
        for (int ni = 0; ni < 4; ++ni) {
            long rbase = m0 + (wm << 6) + (mi << 4) + (lh << 2);
            long col   = n0 + (wn << 6) + (ni << 4) + l16;
#pragma unroll
            for (int r = 0; r < 4; ++r) {
                long row = rbase + r;
                float v = acc[mi][ni][r] * kscale;
                if (outmode == 2) {
                    v += (col < 1024 ? 1.0f : 256.0f / 255.0f) * bias[col & 1023];
                    Cb[(size_t)row * Nc + col] = f2bf(v);
                } else {
                    if (bias) v += bmul * bias[(size_t)(row >> bshift) * Nc + col];
                    if (outmode == 1) Cf[(size_t)row * Nc + col] = v;
                    else              Cb[(size_t)row * Nc + col] = f2bf(v);
                }
            }
        }
    }
}

template<int OUTF32>
__global__ __launch_bounds__(256) void gemm_bt(
    const u16* __restrict__ A, const u16* __restrict__ Bt,
    float* __restrict__ Cf, u16* __restrict__ Cb,
    const float* __restrict__ bias,
    int Nc, int K, int bshift, float kscale, float bmul)
{
    small_body(A, Bt, Cf, Cb, bias, Nc, K, K, K, OUTF32, bshift, kscale, bmul,
               blockIdx.x, blockIdx.y);
}

// Four independent small GEMMs in one launch (96 blocks)
__global__ __launch_bounds__(256) void k_small4(
    const u16* __restrict__ W2cat, const u16* __restrict__ W1rm, u16* __restrict__ W12t,
    const u16* __restrict__ W1bt, const u16* __restrict__ W1ab, u16* __restrict__ W1ct,
    const u16* __restrict__ W2bt, const u16* __restrict__ W2ab, u16* __restrict__ W2ct,
    const u16* __restrict__ s1b, const u16* __restrict__ Wcat, u16* __restrict__ Acat,
    const float* __restrict__ b1)
{
    const int bid = blockIdx.x;
    if (bid < 32) {
        small_body(W2cat, W1rm, nullptr, W12t, nullptr, 512, 1024, 2048, 1024,
                   0, 0, 1.0f, 0.0f, bid >> 2, bid & 3);
    } else if (bid < 64) {
        int r = bid - 32;
        small_body(W1bt, W1ab, nullptr, W1ct, nullptr, 1024, 1024, 1024, 1024,
                   0, 0, 1.0f, 0.0f, r >> 3, r & 7);
    } else if (bid < 80) {
        int r = bid - 64;
        small_body(W2bt, W2ab, nullptr, W2ct, nullptr, 256, 256, 256, 256,
                   0, 0, 1.0f, 0.0f, r >> 1, r & 1);
    } else {
        int r = bid - 80;
        small_body(s1b, Wcat, nullptr, Acat, b1, 2048, 512, 512, 512,
                   2, 0, 1.0f / 255.0f, 0.0f, 0, r);
    }
}

// x[B,T,N] f32 -> h[B,N,T] bf16 transpose + per-(b,t) rowsum (one x read)
__global__ __launch_bounds__(256) void k_trx_rs(
    const float* __restrict__ x, u16* __restrict__ h, u16* __restrict__ s1b)
{
    __shared__ float sm[32][257];
    const int b = blockIdx.y, t0 = blockIdx.x * 32;
    const int tid = threadIdx.x;
    const float* xb = x + ((size_t)b * T_ + t0) * N_;
#pragma unroll 8
    for (int j = 0; j < 32; ++j)
        sm[j][tid] = xb[(size_t)j * N_ + tid];
    __syncthreads();
    const int wave = tid >> 6, lane = tid & 63;
#pragma unroll
    for (int i = 0; i < 8; ++i) {
        int j = wave * 8 + i;
        float s = sm[j][lane] + sm[j][lane + 64] + sm[j][lane + 128] + sm[j][lane + 192];
#pragma unroll
        for (int o = 32; o; o >>= 1) s += __shfl_down(s, o, 64);
        if (lane == 0) s1b[(size_t)b * T_ + t0 + j] = f2bf(s);
    }
    u16 e[32];
#pragma unroll
    for (int j = 0; j < 32; ++j) e[j] = f2bf(sm[j][tid]);
    uint4* dst = (uint4*)(h + ((size_t)b * N_ + tid) * T_ + t0);
    const uint4* src = (const uint4*)e;
#pragma unroll
    for (int v = 0; v < 4; ++v) dst[v] = src[v];
}

// All weight transforms in one launch (2848 blocks of (32,8))
__global__ void k_wtr(const float* __restrict__ Wl1, const float* __restrict__ Wr1,
                      const float* __restrict__ Wl2, const float* __restrict__ Wr2,
                      const float* __restrict__ W1b, const float* __restrict__ W2b,
                      const float* __restrict__ W1a, const float* __restrict__ W2a,
                      u16* __restrict__ Wcat, u16* __restrict__ W1rm,
                      u16* __restrict__ W2cat,
                      u16* __restrict__ W1bt, u16* __restrict__ W2bt,
                      u16* __restrict__ W1ab, u16* __restrict__ W2ab)
{
    __shared__ float tl[32][33], tr[32][33];
    int bid = blockIdx.x;
    const int tx = threadIdx.x, ty = threadIdx.y;
    if (bid < 512) {
        int r0 = (bid >> 5) * 32, c0 = (bid & 31) * 32;
#pragma unroll
        for (int i = 0; i < 4; ++i) {
            int r = r0 + ty + 8 * i;
            float wl = Wl1[(size_t)r * H_ + c0 + tx];
            float wr = Wr1[(size_t)r * H_ + c0 + tx];
            tl[ty + 8 * i][tx] = wl;
            tr[ty + 8 * i][tx] = wl + wr;
            W1rm[(size_t)r * H_ + c0 + tx] = f2bf(wr - wl * (1.0f / 255.0f));
        }
        __syncthreads();
#pragma unroll
        for (int i = 0; i < 4; ++i) {
            size_t o = (size_t)(c0 + ty + 8 * i) * T_ + r0 + tx;
            Wcat[o]                     = f2bf(tl[tx][ty + 8 * i]);
            Wcat[o + (size_t)1024 * T_] = f2bf(tr[tx][ty + 8 * i]);
        }
    } else if (bid < 1536) {
        bid -= 512;
        int r0 = (bid >> 5) * 32, c0 = (bid & 31) * 32;
#pragma unroll
        for (int i = 0; i < 4; ++i) {
            int r = r0 + ty + 8 * i;
            float wl = Wl2[(size_t)r * H_ + c0 + tx];
            float wr = Wr2[(size_t)r * H_ + c0 + tx];
            tl[ty + 8 * i][tx] = wr - wl * (1.0f / 255.0f);
            tr[ty + 8 * i][tx] = wl;
        }
        __syncthreads();
#pragma unroll
        for (int i = 0; i < 4; ++i) {
            size_t o = (size_t)(c0 + ty + 8 * i) * 2048 + r0 + tx;
            W2cat[o]        = f2bf(tl[tx][ty + 8 * i]);
            W2cat[o + 1024] = f2bf(tr[tx][ty + 8 * i]);
        }
    } else if (bid < 2048) {
        bid -= 1536;
        int r0 = (bid >> 4) * 32, c0 = (bid & 15) * 32;
#pragma unroll
        for (int i = 0; i < 4; ++i)
            tl[ty + 8 * i][tx] = W1b[(size_t)(r0 + ty + 8 * i) * T_ + c0 + tx];
        __syncthreads();
#pragma unroll
        for (int i = 0; i < 4; ++i)
            W1bt[(size_t)(c0 + ty + 8 * i) * H_ + r0 + tx] = f2bf(tl[tx][ty + 8 * i]);
    } else if (bid < 2304) {
        bid -= 2048;
        int r0 = (bid >> 5) * 32, c0 = (bid & 31) * 32;
#pragma unroll
        for (int i = 0; i < 4; ++i)
            tl[ty + 8 * i][tx] = W2b[(size_t)(r0 + ty + 8 * i) * H_ + c0 + tx];
        __syncthreads();
#pragma unroll
        for (int i = 0; i < 4; ++i)
            W2bt[(size_t)(c0 + ty + 8 * i) * N_ + r0 + tx] = f2bf(tl[tx][ty + 8 * i]);
    } else {
        int i = (bid - 2304) * 256 + ty * 32 + tx;
        const int n1 = H_ * H_ / 8;
        const float* s; u16* d;
        if (i < n1) { s = W1a; d = W1ab; }
        else        { s = W2a; d = W2ab; i -= n1; }
        float4 a = ((const float4*)s)[2 * i], b = ((const float4*)s)[2 * i + 1];
        u16 e[8] = {f2bf(a.x), f2bf(a.y), f2bf(a.z), f2bf(a.w),
                    f2bf(b.x), f2bf(b.y), f2bf(b.z), f2bf(b.w)};
        ((uint4*)d)[i] = *(const uint4*)e;
    }
}

extern "C" void kernel_launch(void* const* d_in, const int* in_sizes, int n_in,
                              void* d_out, int out_size, void* d_ws, size_t ws_size,
                              hipStream_t stream)
{
    const float* x   = (const float*)d_in[0];
    const float* Wl1 = (const float*)d_in[1];
    const float* Wr1 = (const float*)d_in[2];
    const float* b1  = (const float*)d_in[3];
    const float* Wl2 = (const float*)d_in[4];
    const float* Wr2 = (const float*)d_in[5];
    const float* b2  = (const float*)d_in[6];
    const float* W1a = (const float*)d_in[7];
    const float* W1b = (const float*)d_in[8];
    const float* W2a = (const float*)d_in[9];
    const float* W2b = (const float*)d_in[10];
    float* out = (float*)d_out;

    char* ws = (char*)d_ws;
    size_t off = 0;
    auto alloc = [&](size_t bytes) -> char* {
        char* p = ws + off;
        off += (bytes + 255) & ~(size_t)255;
        return p;
    };

    const size_t BN = (size_t)B_ * N_;   // 32768
    const size_t BT = (size_t)B_ * T_;   // 65536

    u16* h_bf   = (u16*)alloc(BN * T_ * 2);              // h, later q
    u16* h2_bf  = (u16*)alloc(BN * H_ * 2);
    u16* Wcat   = (u16*)alloc((size_t)2048 * T_ * 2);    // [Wl1t ; Wlr1t]
    u16* W1rm   = (u16*)alloc((size_t)T_ * H_ * 2);
    u16* W2cat  = (u16*)alloc((size_t)H_ * 2048 * 2);    // [W2'^T | Wl2^T]
    u16* W1bt   = (u16*)alloc((size_t)T_ * H_ * 2);
    u16* W1ab   = (u16*)alloc((size_t)H_ * H_ * 2);
    u16* W1ct   = (u16*)alloc((size_t)T_ * H_ * 2);
    u16* W2bt   = (u16*)alloc((size_t)H_ * N_ * 2);
    u16* W2ab   = (u16*)alloc((size_t)N_ * N_ * 2);
    u16* W2ct   = (u16*)alloc((size_t)H_ * N_ * 2);
    u16* W12t   = (u16*)alloc((size_t)H_ * T_ * 2);
    u16* s1b    = (u16*)alloc(BT * 2);
    u16* Acat   = (u16*)alloc((size_t)B_ * 2048 * 2);    // [t1b1 | u1s]
    float* t12  = (float*)alloc((size_t)B_ * H_ * 4);

    u16* q_bf = h_bf;

    // --- prep (4 launches) ---
    k_wtr<<<dim3(2848), dim3(32, 8), 0, stream>>>(Wl1, Wr1, Wl2, Wr2, W1b, W2b, W1a, W2a,
                                                  Wcat, W1rm, W2cat, W1bt, W2bt, W1ab, W2ab);
    k_trx_rs<<<dim3(T_ / 32, B_), 256, 0, stream>>>(x, h_bf, s1b);
    k_small4<<<dim3(96), 256, 0, stream>>>(W2cat, W1rm, W12t, W1bt, W1ab, W1ct,
                                           W2bt, W2ab, W2ct, s1b, Wcat, Acat, b1);
    // S23: t12 = [t1b1|u1s] @ [W2'^T|Wl2^T]^T + b2   (K=2048)
    gemm_bt<1><<<dim3(1, H_ / 128), 256, 0, stream>>>(Acat, W2cat, t12, nullptr, b2,
                                                      H_, 2048, 31, 1.0f, 1.0f);

    // --- main chain: one cooperative persistent kernel ---
    void* kargs[] = {(void*)&h_bf, (void*)&W12t, (void*)&t12, (void*)&h2_bf,
                     (void*)&W1ct, (void*)&q_bf, (void*)&W2ct, (void*)&out};
    hipLaunchCooperativeKernel((const void*)mega, dim3(256), dim3(512), kargs, 0, stream);
}

// Round 8
// 369.724 us; speedup vs baseline: 1.4830x; 1.4830x over previous
//
#include <hip/hip_runtime.h>
#include <hip/hip_bf16.h>

#define B_ 128
#define T_ 512
#define N_ 256
#define H_ 1024

typedef unsigned short u16;
typedef __attribute__((ext_vector_type(8))) __bf16 bf16x8;
typedef __attribute__((ext_vector_type(4))) float f32x4;

__device__ __forceinline__ u16 f2bf(float f) {
    unsigned u = __float_as_uint(f);
    u = (u + 0x7FFFu + ((u >> 16) & 1u)) >> 16;
    return (u16)u;
}

__device__ __forceinline__ void g2l16(const void* g, void* l) {
    __builtin_amdgcn_global_load_lds(
        (const __attribute__((address_space(1))) void*)g,
        (__attribute__((address_space(3))) void*)l,
        16, 0, 0);
}

// ===========================================================================
// R8 "ring4" GEMM engine: 256x256 tile, BK=32, 4-slot LDS ring (4 x 32KiB),
// ONE barrier+gate per K-tile, 3-tile-deep prefetch, counted vmcnt(8/4/0).
// C[M,Nc] = act( A[M,K] @ Bt[Nc,K]^T + bias ), A/Bt bf16 row-major [*,K].
// OUT: 0 = bf16 row-major, 1 = f32 row-major, 2 = bf16 transposed q-write.
// ===========================================================================
#define GATE(N) { asm volatile("s_waitcnt vmcnt(" #N ")" ::: "memory"); \
                  __builtin_amdgcn_s_barrier(); }
#define LD4(dst, base) { _Pragma("unroll") for (int i_ = 0; i_ < 4; ++i_) \
    dst[i_] = *(const bf16x8*)(L + (base) + i_ * 512); }
#define MFMA32(RA, RA2, RB) { __builtin_amdgcn_s_setprio(1); \
    _Pragma("unroll") for (int mi_ = 0; mi_ < 4; ++mi_) \
    _Pragma("unroll") for (int ni_ = 0; ni_ < 4; ++ni_) { \
        acc[mi_][ni_]     = __builtin_amdgcn_mfma_f32_16x16x32_bf16(RA[mi_],  RB[ni_], acc[mi_][ni_],     0, 0, 0); \
        acc[4 + mi_][ni_] = __builtin_amdgcn_mfma_f32_16x16x32_bf16(RA2[mi_], RB[ni_], acc[4 + mi_][ni_], 0, 0, 0); } \
    __builtin_amdgcn_s_setprio(0); }
#define STAGE(tile) { const u16* a_ = gA + (size_t)(tile) * 32; \
    const u16* b_ = gB + (size_t)(tile) * 32; \
    const unsigned s_ = (unsigned)(((tile) & 3) * 16384); \
    g2l16(a_, dA0 + s_);  g2l16(a_ + jstr, dA0 + s_ + 4096); \
    g2l16(b_, dB0 + s_);  g2l16(b_ + jstr, dB0 + s_ + 4096); }
#define KTILE(GN) { GATE(GN); \
    bf16x8 ra[4], ra2[4], rb[4]; \
    const unsigned sl = (unsigned)((t & 3) * 16384); \
    LD4(ra,  sl + aoff); \
    LD4(ra2, sl + aoff + 2048); \
    LD4(rb,  sl + boff); \
    if (t + 3 < nt) STAGE(t + 3); \
    MFMA32(ra, ra2, rb); }

template<int ACT, int OUT>
__global__ __launch_bounds__(512, 2) void gemm_r4(
    const u16* __restrict__ A, const u16* __restrict__ Bt,
    float* __restrict__ Cf, u16* __restrict__ Cb,
    const float* __restrict__ bias,
    int Nc, int K, int bshift, int gysh)
{
    __shared__ u16 L[65536];   // 4 slots x (A[256][32] | B[256][32]) = 128 KiB
    const int tid = threadIdx.x;
    const int wave = tid >> 6, lane = tid & 63;
    const int l16 = lane & 15, lh = lane >> 4;
    const int wm = wave >> 2, wn = wave & 3;

    // bijective XCD swizzle (nwg % 8 == 0 for all launches)
    const int qq = (int)gridDim.x >> 3;
    const int orig = (int)blockIdx.x;
    const int wg = (orig & 7) * qq + (orig >> 3);
    const int by = wg & ((1 << gysh) - 1), bx = wg >> gysh;
    const size_t m0 = (size_t)bx * 256, n0 = (size_t)by * 256;

    // read-side swizzled fragment offsets (16B slot ^= (row>>1)&3; row==l16 mod 16)
    const int sx8 = (lh ^ ((l16 >> 1) & 3)) * 8;
    const unsigned aoff = (unsigned)(wm * 4096 + l16 * 32 + sx8);
    const unsigned boff = (unsigned)(8192 + wn * 2048 + l16 * 32 + sx8);

    // staging: thread covers row tid>>2 (and +128), 16B chunk (tid&3), pre-swizzled src
    const int srow = tid >> 2;
    const int sslot = (tid & 3) ^ ((srow >> 1) & 3);
    const size_t jstr = (size_t)128 * K;
    const u16* gA = A + (m0 + srow) * (size_t)K + sslot * 8;
    const u16* gB = Bt + (n0 + srow) * (size_t)K + sslot * 8;
    u16* const dA0 = L + (unsigned)(wave * 512);
    u16* const dB0 = L + 8192 + (unsigned)(wave * 512);

    f32x4 acc[8][4] = {};
    const int nt = K >> 5;   // all uses have nt >= 8

    STAGE(0); STAGE(1); STAGE(2);   // 12 loads in flight

    int t = 0;
    for (; t < nt - 3; ++t) { KTILE(8); }   // steady state: drain tile t, keep 8
    { KTILE(8); ++t; }                      // nt-3: no stage issued (t+3>=nt)
    { KTILE(4); ++t; }                      // nt-2
    { KTILE(0); }                           // nt-1

    // epilogue: C/D layout col = lane&15, row = (lane>>4)*4 + reg
    const size_t NcS = (size_t)Nc;
#pragma unroll
    for (int mi = 0; mi < 8; ++mi) {
#pragma unroll
        for (int ni = 0; ni < 4; ++ni) {
            size_t rbase = m0 + wm * 128 + mi * 16 + lh * 4;
            size_t col   = n0 + wn * 64 + ni * 16 + l16;
            if (OUT == 2) {
                u16 e[4];
#pragma unroll
                for (int rr = 0; rr < 4; ++rr) {
                    float v = acc[mi][ni][rr];
                    v = 1.0f / (1.0f + __expf(-v));
                    e[rr] = f2bf(v);
                }
                size_t qi = ((rbase >> 8) * (size_t)T_ + col) * N_ + (rbase & 255);
                *(uint2*)(Cb + qi) = *(const uint2*)e;
            } else {
#pragma unroll
                for (int rr = 0; rr < 4; ++rr) {
                    size_t row = rbase + rr;
                    float v = acc[mi][ni][rr];
                    if (bias) v += bias[(row >> bshift) * NcS + col];
                    if (ACT) v = 1.0f / (1.0f + __expf(-v));
                    if (OUT == 1) Cf[row * NcS + col] = v;
                    else          Cb[row * NcS + col] = f2bf(v);
                }
            }
        }
    }
}

// ---------------------------------------------------------------------------
// 128x128 2-barrier GEMM body (device fn) for small GEMMs.
// ---------------------------------------------------------------------------
__device__ __forceinline__ void small_body(
    const u16* __restrict__ A, const u16* __restrict__ Bt,
    float* __restrict__ Cf, u16* __restrict__ Cb,
    const float* __restrict__ bias,
    int Nc, int K, int lda, int ldb, int outmode, int bshift,
    float kscale, float bmul, int bx, int by)
{
    __shared__ u16 lA[128 * 64];
    __shared__ u16 lB[128 * 64];
    const int tid = threadIdx.x;
    const int wave = tid >> 6, lane = tid & 63;
    const int l16 = lane & 15, lh = lane >> 4;
    const int wm = wave >> 1, wn = wave & 1;
    const long m0 = (long)bx * 128;
    const long n0 = (long)by * 128;

    f32x4 acc[4][4] = {};

    for (int k0 = 0; k0 < K; k0 += 64) {
#pragma unroll
        for (int j = 0; j < 4; ++j) {
            int c = j * 256 + tid;
            int row = c >> 3, col = (c & 7) << 3;
            g2l16(A  + (m0 + row) * (size_t)lda + k0 + col, &lA[(size_t)(j * 256 + (wave << 6)) * 8]);
            g2l16(Bt + (n0 + row) * (size_t)ldb + k0 + col, &lB[(size_t)(j * 256 + (wave << 6)) * 8]);
        }
        __syncthreads();
#pragma unroll
        for (int s = 0; s < 2; ++s) {
            bf16x8 af[4], bfr[4];
#pragma unroll
            for (int mi = 0; mi < 4; ++mi)
                af[mi] = *(const bf16x8*)&lA[((wm << 6) + (mi << 4) + l16) * 64 + s * 32 + (lh << 3)];
#pragma unroll
            for (int ni = 0; ni < 4; ++ni)
                bfr[ni] = *(const bf16x8*)&lB[((wn << 6) + (ni << 4) + l16) * 64 + s * 32 + (lh << 3)];
#pragma unroll
            for (int mi = 0; mi < 4; ++mi)
#pragma unroll
                for (int ni = 0; ni < 4; ++ni)
                    acc[mi][ni] = __builtin_amdgcn_mfma_f32_16x16x32_bf16(af[mi], bfr[ni], acc[mi][ni], 0, 0, 0);
        }
        __syncthreads();
    }

#pragma unroll
    for (int mi = 0; mi < 4; ++mi) {
#pragma unroll
        for (int ni = 0; ni < 4; ++ni) {
            long rbase = m0 + (wm << 6) + (mi << 4) + (lh << 2);
            long col   = n0 + (wn << 6) + (ni << 4) + l16;
#pragma unroll
            for (int r = 0; r < 4; ++r) {
                long row = rbase + r;
                float v = acc[mi][ni][r] * kscale;
                if (outmode == 2) {
                    v += (col < 1024 ? 1.0f : 256.0f / 255.0f) * bias[col & 1023];
                    Cb[(size_t)row * Nc + col] = f2bf(v);
                } else {
                    if (bias) v += bmul * bias[(size_t)(row >> bshift) * Nc + col];
                    if (outmode == 1) Cf[(size_t)row * Nc + col] = v;
                    else              Cb[(size_t)row * Nc + col] = f2bf(v);
                }
            }
        }
    }
}

template<int OUTF32>
__global__ __launch_bounds__(256) void gemm_bt(
    const u16* __restrict__ A, const u16* __restrict__ Bt,
    float* __restrict__ Cf, u16* __restrict__ Cb,
    const float* __restrict__ bias,
    int Nc, int K, int bshift, float kscale, float bmul)
{
    small_body(A, Bt, Cf, Cb, bias, Nc, K, K, K, OUTF32, bshift, kscale, bmul,
               blockIdx.x, blockIdx.y);
}

// Four independent small GEMMs in one launch (96 blocks)
__global__ __launch_bounds__(256) void k_small4(
    const u16* __restrict__ W2cat, const u16* __restrict__ W1rm, u16* __restrict__ W12t,
    const u16* __restrict__ W1bt, const u16* __restrict__ W1ab, u16* __restrict__ W1ct,
    const u16* __restrict__ W2bt, const u16* __restrict__ W2ab, u16* __restrict__ W2ct,
    const u16* __restrict__ s1b, const u16* __restrict__ Wcat, u16* __restrict__ Acat,
    const float* __restrict__ b1)
{
    const int bid = blockIdx.x;
    if (bid < 32) {
        small_body(W2cat, W1rm, nullptr, W12t, nullptr, 512, 1024, 2048, 1024,
                   0, 0, 1.0f, 0.0f, bid >> 2, bid & 3);
    } else if (bid < 64) {
        int r = bid - 32;
        small_body(W1bt, W1ab, nullptr, W1ct, nullptr, 1024, 1024, 1024, 1024,
                   0, 0, 1.0f, 0.0f, r >> 3, r & 7);
    } else if (bid < 80) {
        int r = bid - 64;
        small_body(W2bt, W2ab, nullptr, W2ct, nullptr, 256, 256, 256, 256,
                   0, 0, 1.0f, 0.0f, r >> 1, r & 1);
    } else {
        int r = bid - 80;
        small_body(s1b, Wcat, nullptr, Acat, b1, 2048, 512, 512, 512,
                   2, 0, 1.0f / 255.0f, 0.0f, 0, r);
    }
}

// x[B,T,N] f32 -> h[B,N,T] bf16 transpose + per-(b,t) rowsum (one x read)
__global__ __launch_bounds__(256) void k_trx_rs(
    const float* __restrict__ x, u16* __restrict__ h, u16* __restrict__ s1b)
{
    __shared__ float sm[32][257];
    const int b = blockIdx.y, t0 = blockIdx.x * 32;
    const int tid = threadIdx.x;
    const float* xb = x + ((size_t)b * T_ + t0) * N_;
#pragma unroll 8
    for (int j = 0; j < 32; ++j)
        sm[j][tid] = xb[(size_t)j * N_ + tid];
    __syncthreads();
    const int wave = tid >> 6, lane = tid & 63;
#pragma unroll
    for (int i = 0; i < 8; ++i) {
        int j = wave * 8 + i;
        float s = sm[j][lane] + sm[j][lane + 64] + sm[j][lane + 128] + sm[j][lane + 192];
#pragma unroll
        for (int o = 32; o; o >>= 1) s += __shfl_down(s, o, 64);
        if (lane == 0) s1b[(size_t)b * T_ + t0 + j] = f2bf(s);
    }
    u16 e[32];
#pragma unroll
    for (int j = 0; j < 32; ++j) e[j] = f2bf(sm[j][tid]);
    uint4* dst = (uint4*)(h + ((size_t)b * N_ + tid) * T_ + t0);
    const uint4* src = (const uint4*)e;
#pragma unroll
    for (int v = 0; v < 4; ++v) dst[v] = src[v];
}

// All weight transforms in one launch (2848 blocks of (32,8))
__global__ void k_wtr(const float* __restrict__ Wl1, const float* __restrict__ Wr1,
                      const float* __restrict__ Wl2, const float* __restrict__ Wr2,
                      const float* __restrict__ W1b, const float* __restrict__ W2b,
                      const float* __restrict__ W1a, const float* __restrict__ W2a,
                      u16* __restrict__ Wcat, u16* __restrict__ W1rm,
                      u16* __restrict__ W2cat,
                      u16* __restrict__ W1bt, u16* __restrict__ W2bt,
                      u16* __restrict__ W1ab, u16* __restrict__ W2ab)
{
    __shared__ float tl[32][33], tr[32][33];
    int bid = blockIdx.x;
    const int tx = threadIdx.x, ty = threadIdx.y;
    if (bid < 512) {
        int r0 = (bid >> 5) * 32, c0 = (bid & 31) * 32;
#pragma unroll
        for (int i = 0; i < 4; ++i) {
            int r = r0 + ty + 8 * i;
            float wl = Wl1[(size_t)r * H_ + c0 + tx];
            float wr = Wr1[(size_t)r * H_ + c0 + tx];
            tl[ty + 8 * i][tx] = wl;
            tr[ty + 8 * i][tx] = wl + wr;
            W1rm[(size_t)r * H_ + c0 + tx] = f2bf(wr - wl * (1.0f / 255.0f));
        }
        __syncthreads();
#pragma unroll
        for (int i = 0; i < 4; ++i) {
            size_t o = (size_t)(c0 + ty + 8 * i) * T_ + r0 + tx;
            Wcat[o]                     = f2bf(tl[tx][ty + 8 * i]);
            Wcat[o + (size_t)1024 * T_] = f2bf(tr[tx][ty + 8 * i]);
        }
    } else if (bid < 1536) {
        bid -= 512;
        int r0 = (bid >> 5) * 32, c0 = (bid & 31) * 32;
#pragma unroll
        for (int i = 0; i < 4; ++i) {
            int r = r0 + ty + 8 * i;
            float wl = Wl2[(size_t)r * H_ + c0 + tx];
            float wr = Wr2[(size_t)r * H_ + c0 + tx];
            tl[ty + 8 * i][tx] = wr - wl * (1.0f / 255.0f);
            tr[ty + 8 * i][tx] = wl;
        }
        __syncthreads();
#pragma unroll
        for (int i = 0; i < 4; ++i) {
            size_t o = (size_t)(c0 + ty + 8 * i) * 2048 + r0 + tx;
            W2cat[o]        = f2bf(tl[tx][ty + 8 * i]);
            W2cat[o + 1024] = f2bf(tr[tx][ty + 8 * i]);
        }
    } else if (bid < 2048) {
        bid -= 1536;
        int r0 = (bid >> 4) * 32, c0 = (bid & 15) * 32;
#pragma unroll
        for (int i = 0; i < 4; ++i)
            tl[ty + 8 * i][tx] = W1b[(size_t)(r0 + ty + 8 * i) * T_ + c0 + tx];
        __syncthreads();
#pragma unroll
        for (int i = 0; i < 4; ++i)
            W1bt[(size_t)(c0 + ty + 8 * i) * H_ + r0 + tx] = f2bf(tl[tx][ty + 8 * i]);
    } else if (bid < 2304) {
        bid -= 2048;
        int r0 = (bid >> 5) * 32, c0 = (bid & 31) * 32;
#pragma unroll
        for (int i = 0; i < 4; ++i)
            tl[ty + 8 * i][tx] = W2b[(size_t)(r0 + ty + 8 * i) * H_ + c0 + tx];
        __syncthreads();
#pragma unroll
        for (int i = 0; i < 4; ++i)
            W2bt[(size_t)(c0 + ty + 8 * i) * N_ + r0 + tx] = f2bf(tl[tx][ty + 8 * i]);
    } else {
        int i = (bid - 2304) * 256 + ty * 32 + tx;
        const int n1 = H_ * H_ / 8;
        const float* s; u16* d;
        if (i < n1) { s = W1a; d = W1ab; }
        else        { s = W2a; d = W2ab; i -= n1; }
        float4 a = ((const float4*)s)[2 * i], b = ((const float4*)s)[2 * i + 1];
        u16 e[8] = {f2bf(a.x), f2bf(a.y), f2bf(a.z), f2bf(a.w),
                    f2bf(b.x), f2bf(b.y), f2bf(b.z), f2bf(b.w)};
        ((uint4*)d)[i] = *(const uint4*)e;
    }
}

extern "C" void kernel_launch(void* const* d_in, const int* in_sizes, int n_in,
                              void* d_out, int out_size, void* d_ws, size_t ws_size,
                              hipStream_t stream)
{
    const float* x   = (const float*)d_in[0];
    const float* Wl1 = (const float*)d_in[1];
    const float* Wr1 = (const float*)d_in[2];
    const float* b1  = (const float*)d_in[3];
    const float* Wl2 = (const float*)d_in[4];
    const float* Wr2 = (const float*)d_in[5];
    const float* b2  = (const float*)d_in[6];
    const float* W1a = (const float*)d_in[7];
    const float* W1b = (const float*)d_in[8];
    const float* W2a = (const float*)d_in[9];
    const float* W2b = (const float*)d_in[10];
    float* out = (float*)d_out;

    char* ws = (char*)d_ws;
    size_t off = 0;
    auto alloc = [&](size_t bytes) -> char* {
        char* p = ws + off;
        off += (bytes + 255) & ~(size_t)255;
        return p;
    };

    const size_t BN = (size_t)B_ * N_;   // 32768
    const size_t BT = (size_t)B_ * T_;   // 65536

    u16* h_bf   = (u16*)alloc(BN * T_ * 2);              // h, later q
    u16* h2_bf  = (u16*)alloc(BN * H_ * 2);
    u16* Wcat   = (u16*)alloc((size_t)2048 * T_ * 2);    // [Wl1t ; Wlr1t]
    u16* W1rm   = (u16*)alloc((size_t)T_ * H_ * 2);
    u16* W2cat  = (u16*)alloc((size_t)H_ * 2048 * 2);    // [W2'^T | Wl2^T]
    u16* W1bt   = (u16*)alloc((size_t)T_ * H_ * 2);
    u16* W1ab   = (u16*)alloc((size_t)H_ * H_ * 2);
    u16* W1ct   = (u16*)alloc((size_t)T_ * H_ * 2);
    u16* W2bt   = (u16*)alloc((size_t)H_ * N_ * 2);
    u16* W2ab   = (u16*)alloc((size_t)N_ * N_ * 2);
    u16* W2ct   = (u16*)alloc((size_t)H_ * N_ * 2);
    u16* W12t   = (u16*)alloc((size_t)H_ * T_ * 2);
    u16* s1b    = (u16*)alloc(BT * 2);
    u16* Acat   = (u16*)alloc((size_t)B_ * 2048 * 2);    // [t1b1 | u1s]
    float* t12  = (float*)alloc((size_t)B_ * H_ * 4);

    u16* q_bf = h_bf;

    // --- prep (4 launches) ---
    k_wtr<<<dim3(2848), dim3(32, 8), 0, stream>>>(Wl1, Wr1, Wl2, Wr2, W1b, W2b, W1a, W2a,
                                                  Wcat, W1rm, W2cat, W1bt, W2bt, W1ab, W2ab);
    k_trx_rs<<<dim3(T_ / 32, B_), 256, 0, stream>>>(x, h_bf, s1b);
    k_small4<<<dim3(96), 256, 0, stream>>>(W2cat, W1rm, W12t, W1bt, W1ab, W1ct,
                                           W2bt, W2ab, W2ct, s1b, Wcat, Acat, b1);
    // S23: t12 = [t1b1|u1s] @ [W2'^T|Wl2^T]^T + b2   (K=2048)
    gemm_bt<1><<<dim3(1, H_ / 128), 256, 0, stream>>>(Acat, W2cat, t12, nullptr, b2,
                                                      H_, 2048, 31, 1.0f, 1.0f);

    // --- main chain (3 ring4 GEMMs, split launches) ---
    // GA: h2 = h @ W12 + t12         [32768,1024] K=512  (nt=16)
    gemm_r4<0, 0><<<dim3(128 * 4), 512, 0, stream>>>(h_bf, W12t, nullptr, h2_bf, t12, H_, T_, 8, 2);
    // GB: q = sigma(h2 @ W1c), transposed q[B,T,N]   K=1024 (nt=32)
    gemm_r4<1, 2><<<dim3(128 * 2), 512, 0, stream>>>(h2_bf, W1ct, nullptr, q_bf, nullptr, T_, H_, 0, 1);
    // GC: out = sigma(q @ W2c) f32   [65536,1024] K=256  (nt=8)
    gemm_r4<1, 1><<<dim3(256 * 4), 512, 0, stream>>>(q_bf, W2ct, out, nullptr, nullptr, H_, N_, 0, 2);
}

// Round 9
// 292.322 us; speedup vs baseline: 1.8757x; 1.2648x over previous
//
#include <hip/hip_runtime.h>
#include <hip/hip_bf16.h>

#define B_ 128
#define T_ 512
#define N_ 256
#define H_ 1024

typedef unsigned short u16;
typedef __attribute__((ext_vector_type(8))) __bf16 bf16x8;
typedef __attribute__((ext_vector_type(4))) float f32x4;

__device__ __forceinline__ u16 f2bf(float f) {
    unsigned u = __float_as_uint(f);
    u = (u + 0x7FFFu + ((u >> 16) & 1u)) >> 16;
    return (u16)u;
}

__device__ __forceinline__ void g2l16(const void* g, void* l) {
    __builtin_amdgcn_global_load_lds(
        (const __attribute__((address_space(1))) void*)g,
        (__attribute__((address_space(3))) void*)l,
        16, 0, 0);
}

// ===========================================================================
// R9 "e2" engine: 256x128 tile, 8 waves of 64x64, BK=32, 2-slot LDS ring
// (2 x 24 KiB = 48 KiB) -> 2 blocks/CU for inter-block pipe overlap (m114).
// One GATE(0)+barrier per K-tile; stage of tile t+1 issued inside tile t.
// C[M,Nc] = act( A[M,K] @ Bt[Nc,K]^T + bias ), A/Bt bf16 row-major [*,K].
// OUT: 0 = bf16 row-major, 1 = f32 row-major, 2 = bf16 transposed q-write.
// ===========================================================================
#define ASLOT 12288u   // u16 per ring slot: A[256][32] (8192) + B[128][32] (4096)

#define GATE(N) { asm volatile("s_waitcnt vmcnt(" #N ")" ::: "memory"); \
                  __builtin_amdgcn_s_barrier(); }
#define LD4(dst, base) { _Pragma("unroll") for (int i_ = 0; i_ < 4; ++i_) \
    dst[i_] = *(const bf16x8*)(L + (base) + i_ * 512); }
#define STAGE(tile) { const u16* a_ = gA + (size_t)(tile) * 32; \
    const u16* b_ = gB + (size_t)(tile) * 32; \
    const unsigned s_ = (unsigned)(((tile) & 1) * ASLOT); \
    g2l16(a_, dA0 + s_);  g2l16(a_ + jstr, dA0 + s_ + 4096); \
    g2l16(b_, dB0 + s_); }

template<int ACT, int OUT>
__global__ __launch_bounds__(512, 2) void gemm_e2(
    const u16* __restrict__ A, const u16* __restrict__ Bt,
    float* __restrict__ Cf, u16* __restrict__ Cb,
    const float* __restrict__ bias,
    int Nc, int K, int bshift, int gysh)
{
    __shared__ u16 L[24576];   // 48 KiB
    const int tid = threadIdx.x;
    const int wave = tid >> 6, lane = tid & 63;
    const int l16 = lane & 15, lh = lane >> 4;
    const int wm = wave >> 1, wn = wave & 1;   // 4x2 wave grid, 64x64 each

    // bijective XCD swizzle (all grids are multiples of 8)
    const int qq = (int)gridDim.x >> 3;
    const int orig = (int)blockIdx.x;
    const int wg = (orig & 7) * qq + (orig >> 3);
    const int by = wg & ((1 << gysh) - 1), bx = wg >> gysh;
    const size_t m0 = (size_t)bx * 256, n0 = (size_t)by * 128;

    // read-side swizzled fragment offsets (16B slot ^= (row>>1)&3)
    const int sx8 = (lh ^ ((l16 >> 1) & 3)) * 8;
    const unsigned aoff = (unsigned)(wm * 2048 + l16 * 32 + sx8);
    const unsigned boff = (unsigned)(8192 + wn * 2048 + l16 * 32 + sx8);

    // staging: thread row tid>>2 (A also +128), 16B chunk tid&3, pre-swz src
    const int srow = tid >> 2;
    const int sslot = (tid & 3) ^ ((srow >> 1) & 3);
    const size_t jstr = (size_t)128 * K;
    const u16* gA = A + (m0 + srow) * (size_t)K + sslot * 8;
    const u16* gB = Bt + (n0 + srow) * (size_t)K + sslot * 8;
    u16* const dA0 = L + (unsigned)(wave * 512);
    u16* const dB0 = L + 8192 + (unsigned)(wave * 512);

    f32x4 acc[4][4] = {};
    const int nt = K >> 5;

    STAGE(0);
    for (int t = 0; t < nt; ++t) {
        GATE(0);   // tile t landed (issued one full tile earlier)
        const unsigned sl = (unsigned)((t & 1) * ASLOT);
        bf16x8 ra[4], rb[4];
        LD4(ra, sl + aoff);
        LD4(rb, sl + boff);
        if (t + 1 < nt) STAGE(t + 1);
        __builtin_amdgcn_s_setprio(1);
#pragma unroll
        for (int mi = 0; mi < 4; ++mi)
#pragma unroll
            for (int ni = 0; ni < 4; ++ni)
                acc[mi][ni] = __builtin_amdgcn_mfma_f32_16x16x32_bf16(
                    ra[mi], rb[ni], acc[mi][ni], 0, 0, 0);
        __builtin_amdgcn_s_setprio(0);
    }

    // epilogue: C/D layout col = lane&15, row = (lane>>4)*4 + reg
    const size_t NcS = (size_t)Nc;
#pragma unroll
    for (int mi = 0; mi < 4; ++mi) {
#pragma unroll
        for (int ni = 0; ni < 4; ++ni) {
            size_t rbase = m0 + wm * 64 + mi * 16 + lh * 4;
            size_t col   = n0 + wn * 64 + ni * 16 + l16;
            if (OUT == 2) {
                u16 e[4];
#pragma unroll
                for (int rr = 0; rr < 4; ++rr) {
                    float v = acc[mi][ni][rr];
                    v = 1.0f / (1.0f + __expf(-v));
                    e[rr] = f2bf(v);
                }
                size_t qi = ((rbase >> 8) * (size_t)T_ + col) * N_ + (rbase & 255);
                *(uint2*)(Cb + qi) = *(const uint2*)e;
            } else {
#pragma unroll
                for (int rr = 0; rr < 4; ++rr) {
                    size_t row = rbase + rr;
                    float v = acc[mi][ni][rr];
                    if (bias) v += bias[(row >> bshift) * NcS + col];
                    if (ACT) v = 1.0f / (1.0f + __expf(-v));
                    if (OUT == 1) Cf[row * NcS + col] = v;
                    else          Cb[row * NcS + col] = f2bf(v);
                }
            }
        }
    }
}

// ---------------------------------------------------------------------------
// 128x128 2-barrier GEMM body (device fn) for small GEMMs.
// ---------------------------------------------------------------------------
__device__ __forceinline__ void small_body(
    const u16* __restrict__ A, const u16* __restrict__ Bt,
    float* __restrict__ Cf, u16* __restrict__ Cb,
    const float* __restrict__ bias,
    int Nc, int K, int lda, int ldb, int outmode, int bshift,
    float kscale, float bmul, int bx, int by)
{
    __shared__ u16 lA[128 * 64];
    __shared__ u16 lB[128 * 64];
    const int tid = threadIdx.x;
    const int wave = tid >> 6, lane = tid & 63;
    const int l16 = lane & 15, lh = lane >> 4;
    const int wm = wave >> 1, wn = wave & 1;
    const long m0 = (long)bx * 128;
    const long n0 = (long)by * 128;

    f32x4 acc[4][4] = {};

    for (int k0 = 0; k0 < K; k0 += 64) {
#pragma unroll
        for (int j = 0; j < 4; ++j) {
            int c = j * 256 + tid;
            int row = c >> 3, col = (c & 7) << 3;
            g2l16(A  + (m0 + row) * (size_t)lda + k0 + col, &lA[(size_t)(j * 256 + (wave << 6)) * 8]);
            g2l16(Bt + (n0 + row) * (size_t)ldb + k0 + col, &lB[(size_t)(j * 256 + (wave << 6)) * 8]);
        }
        __syncthreads();
#pragma unroll
        for (int s = 0; s < 2; ++s) {
            bf16x8 af[4], bfr[4];
#pragma unroll
            for (int mi = 0; mi < 4; ++mi)
                af[mi] = *(const bf16x8*)&lA[((wm << 6) + (mi << 4) + l16) * 64 + s * 32 + (lh << 3)];
#pragma unroll
            for (int ni = 0; ni < 4; ++ni)
                bfr[ni] = *(const bf16x8*)&lB[((wn << 6) + (ni << 4) + l16) * 64 + s * 32 + (lh << 3)];
#pragma unroll
            for (int mi = 0; mi < 4; ++mi)
#pragma unroll
                for (int ni = 0; ni < 4; ++ni)
                    acc[mi][ni] = __builtin_amdgcn_mfma_f32_16x16x32_bf16(af[mi], bfr[ni], acc[mi][ni], 0, 0, 0);
        }
        __syncthreads();
    }

#pragma unroll
    for (int mi = 0; mi < 4; ++mi) {
#pragma unroll
        for (int ni = 0; ni < 4; ++ni) {
            long rbase = m0 + (wm << 6) + (mi << 4) + (lh << 2);
            long col   = n0 + (wn << 6) + (ni << 4) + l16;
#pragma unroll
            for (int r = 0; r < 4; ++r) {
                long row = rbase + r;
                float v = acc[mi][ni][r] * kscale;
                if (outmode == 2) {
                    v += (col < 1024 ? 1.0f : 256.0f / 255.0f) * bias[col & 1023];
                    Cb[(size_t)row * Nc + col] = f2bf(v);
                } else {
                    if (bias) v += bmul * bias[(size_t)(row >> bshift) * Nc + col];
                    if (outmode == 1) Cf[(size_t)row * Nc + col] = v;
                    else              Cb[(size_t)row * Nc + col] = f2bf(v);
                }
            }
        }
    }
}

template<int OUTF32>
__global__ __launch_bounds__(256) void gemm_bt(
    const u16* __restrict__ A, const u16* __restrict__ Bt,
    float* __restrict__ Cf, u16* __restrict__ Cb,
    const float* __restrict__ bias,
    int Nc, int K, int bshift, float kscale, float bmul)
{
    small_body(A, Bt, Cf, Cb, bias, Nc, K, K, K, OUTF32, bshift, kscale, bmul,
               blockIdx.x, blockIdx.y);
}

// Four independent small GEMMs in one launch (96 blocks)
__global__ __launch_bounds__(256) void k_small4(
    const u16* __restrict__ W2cat, const u16* __restrict__ W1rm, u16* __restrict__ W12t,
    const u16* __restrict__ W1bt, const u16* __restrict__ W1ab, u16* __restrict__ W1ct,
    const u16* __restrict__ W2bt, const u16* __restrict__ W2ab, u16* __restrict__ W2ct,
    const u16* __restrict__ s1b, const u16* __restrict__ Wcat, u16* __restrict__ Acat,
    const float* __restrict__ b1)
{
    const int bid = blockIdx.x;
    if (bid < 32) {
        small_body(W2cat, W1rm, nullptr, W12t, nullptr, 512, 1024, 2048, 1024,
                   0, 0, 1.0f, 0.0f, bid >> 2, bid & 3);
    } else if (bid < 64) {
        int r = bid - 32;
        small_body(W1bt, W1ab, nullptr, W1ct, nullptr, 1024, 1024, 1024, 1024,
                   0, 0, 1.0f, 0.0f, r >> 3, r & 7);
    } else if (bid < 80) {
        int r = bid - 64;
        small_body(W2bt, W2ab, nullptr, W2ct, nullptr, 256, 256, 256, 256,
                   0, 0, 1.0f, 0.0f, r >> 1, r & 1);
    } else {
        int r = bid - 80;
        small_body(s1b, Wcat, nullptr, Acat, b1, 2048, 512, 512, 512,
                   2, 0, 1.0f / 255.0f, 0.0f, 0, r);
    }
}

// x[B,T,N] f32 -> h[B,N,T] bf16 transpose + per-(b,t) rowsum (one x read)
__global__ __launch_bounds__(256) void k_trx_rs(
    const float* __restrict__ x, u16* __restrict__ h, u16* __restrict__ s1b)
{
    __shared__ float sm[32][257];
    const int b = blockIdx.y, t0 = blockIdx.x * 32;
    const int tid = threadIdx.x;
    const float* xb = x + ((size_t)b * T_ + t0) * N_;
#pragma unroll 8
    for (int j = 0; j < 32; ++j)
        sm[j][tid] = xb[(size_t)j * N_ + tid];
    __syncthreads();
    const int wave = tid >> 6, lane = tid & 63;
#pragma unroll
    for (int i = 0; i < 8; ++i) {
        int j = wave * 8 + i;
        float s = sm[j][lane] + sm[j][lane + 64] + sm[j][lane + 128] + sm[j][lane + 192];
#pragma unroll
        for (int o = 32; o; o >>= 1) s += __shfl_down(s, o, 64);
        if (lane == 0) s1b[(size_t)b * T_ + t0 + j] = f2bf(s);
    }
    u16 e[32];
#pragma unroll
    for (int j = 0; j < 32; ++j) e[j] = f2bf(sm[j][tid]);
    uint4* dst = (uint4*)(h + ((size_t)b * N_ + tid) * T_ + t0);
    const uint4* src = (const uint4*)e;
#pragma unroll
    for (int v = 0; v < 4; ++v) dst[v] = src[v];
}

// All weight transforms in one launch (2848 blocks of (32,8))
__global__ void k_wtr(const float* __restrict__ Wl1, const float* __restrict__ Wr1,
                      const float* __restrict__ Wl2, const float* __restrict__ Wr2,
                      const float* __restrict__ W1b, const float* __restrict__ W2b,
                      const float* __restrict__ W1a, const float* __restrict__ W2a,
                      u16* __restrict__ Wcat, u16* __restrict__ W1rm,
                      u16* __restrict__ W2cat,
                      u16* __restrict__ W1bt, u16* __restrict__ W2bt,
                      u16* __restrict__ W1ab, u16* __restrict__ W2ab)
{
    __shared__ float tl[32][33], tr[32][33];
    int bid = blockIdx.x;
    const int tx = threadIdx.x, ty = threadIdx.y;
    if (bid < 512) {
        int r0 = (bid >> 5) * 32, c0 = (bid & 31) * 32;
#pragma unroll
        for (int i = 0; i < 4; ++i) {
            int r = r0 + ty + 8 * i;
            float wl = Wl1[(size_t)r * H_ + c0 + tx];
            float wr = Wr1[(size_t)r * H_ + c0 + tx];
            tl[ty + 8 * i][tx] = wl;
            tr[ty + 8 * i][tx] = wl + wr;
            W1rm[(size_t)r * H_ + c0 + tx] = f2bf(wr - wl * (1.0f / 255.0f));
        }
        __syncthreads();
#pragma unroll
        for (int i = 0; i < 4; ++i) {
            size_t o = (size_t)(c0 + ty + 8 * i) * T_ + r0 + tx;
            Wcat[o]                     = f2bf(tl[tx][ty + 8 * i]);
            Wcat[o + (size_t)1024 * T_] = f2bf(tr[tx][ty + 8 * i]);
        }
    } else if (bid < 1536) {
        bid -= 512;
        int r0 = (bid >> 5) * 32, c0 = (bid & 31) * 32;
#pragma unroll
        for (int i = 0; i < 4; ++i) {
            int r = r0 + ty + 8 * i;
            float wl = Wl2[(size_t)r * H_ + c0 + tx];
            float wr = Wr2[(size_t)r * H_ + c0 + tx];
            tl[ty + 8 * i][tx] = wr - wl * (1.0f / 255.0f);
            tr[ty + 8 * i][tx] = wl;
        }
        __syncthreads();
#pragma unroll
        for (int i = 0; i < 4; ++i) {
            size_t o = (size_t)(c0 + ty + 8 * i) * 2048 + r0 + tx;
            W2cat[o]        = f2bf(tl[tx][ty + 8 * i]);
            W2cat[o + 1024] = f2bf(tr[tx][ty + 8 * i]);
        }
    } else if (bid < 2048) {
        bid -= 1536;
        int r0 = (bid >> 4) * 32, c0 = (bid & 15) * 32;
#pragma unroll
        for (int i = 0; i < 4; ++i)
            tl[ty + 8 * i][tx] = W1b[(size_t)(r0 + ty + 8 * i) * T_ + c0 + tx];
        __syncthreads();
#pragma unroll
        for (int i = 0; i < 4; ++i)
            W1bt[(size_t)(c0 + ty + 8 * i) * H_ + r0 + tx] = f2bf(tl[tx][ty + 8 * i]);
    } else if (bid < 2304) {
        bid -= 2048;
        int r0 = (bid >> 5) * 32, c0 = (bid & 31) * 32;
#pragma unroll
        for (int i = 0; i < 4; ++i)
            tl[ty + 8 * i][tx] = W2b[(size_t)(r0 + ty + 8 * i) * H_ + c0 + tx];
        __syncthreads();
#pragma unroll
        for (int i = 0; i < 4; ++i)
            W2bt[(size_t)(c0 + ty + 8 * i) * N_ + r0 + tx] = f2bf(tl[tx][ty + 8 * i]);
    } else {
        int i = (bid - 2304) * 256 + ty * 32 + tx;
        const int n1 = H_ * H_ / 8;
        const float* s; u16* d;
        if (i < n1) { s = W1a; d = W1ab; }
        else        { s = W2a; d = W2ab; i -= n1; }
        float4 a = ((const float4*)s)[2 * i], b = ((const float4*)s)[2 * i + 1];
        u16 e[8] = {f2bf(a.x), f2bf(a.y), f2bf(a.z), f2bf(a.w),
                    f2bf(b.x), f2bf(b.y), f2bf(b.z), f2bf(b.w)};
        ((uint4*)d)[i] = *(const uint4*)e;
    }
}

extern "C" void kernel_launch(void* const* d_in, const int* in_sizes, int n_in,
                              void* d_out, int out_size, void* d_ws, size_t ws_size,
                              hipStream_t stream)
{
    const float* x   = (const float*)d_in[0];
    const float* Wl1 = (const float*)d_in[1];
    const float* Wr1 = (const float*)d_in[2];
    const float* b1  = (const float*)d_in[3];
    const float* Wl2 = (const float*)d_in[4];
    const float* Wr2 = (const float*)d_in[5];
    const float* b2  = (const float*)d_in[6];
    const float* W1a = (const float*)d_in[7];
    const float* W1b = (const float*)d_in[8];
    const float* W2a = (const float*)d_in[9];
    const float* W2b = (const float*)d_in[10];
    float* out = (float*)d_out;

    char* ws = (char*)d_ws;
    size_t off = 0;
    auto alloc = [&](size_t bytes) -> char* {
        char* p = ws + off;
        off += (bytes + 255) & ~(size_t)255;
        return p;
    };

    const size_t BN = (size_t)B_ * N_;   // 32768
    const size_t BT = (size_t)B_ * T_;   // 65536

    u16* h_bf   = (u16*)alloc(BN * T_ * 2);              // h, later q
    u16* h2_bf  = (u16*)alloc(BN * H_ * 2);
    u16* Wcat   = (u16*)alloc((size_t)2048 * T_ * 2);    // [Wl1t ; Wlr1t]
    u16* W1rm   = (u16*)alloc((size_t)T_ * H_ * 2);
    u16* W2cat  = (u16*)alloc((size_t)H_ * 2048 * 2);    // [W2'^T | Wl2^T]
    u16* W1bt   = (u16*)alloc((size_t)T_ * H_ * 2);
    u16* W1ab   = (u16*)alloc((size_t)H_ * H_ * 2);
    u16* W1ct   = (u16*)alloc((size_t)T_ * H_ * 2);
    u16* W2bt   = (u16*)alloc((size_t)H_ * N_ * 2);
    u16* W2ab   = (u16*)alloc((size_t)N_ * N_ * 2);
    u16* W2ct   = (u16*)alloc((size_t)H_ * N_ * 2);
    u16* W12t   = (u16*)alloc((size_t)H_ * T_ * 2);
    u16* s1b    = (u16*)alloc(BT * 2);
    u16* Acat   = (u16*)alloc((size_t)B_ * 2048 * 2);    // [t1b1 | u1s]
    float* t12  = (float*)alloc((size_t)B_ * H_ * 4);

    u16* q_bf = h_bf;

    // --- prep (4 launches) ---
    k_wtr<<<dim3(2848), dim3(32, 8), 0, stream>>>(Wl1, Wr1, Wl2, Wr2, W1b, W2b, W1a, W2a,
                                                  Wcat, W1rm, W2cat, W1bt, W2bt, W1ab, W2ab);
    k_trx_rs<<<dim3(T_ / 32, B_), 256, 0, stream>>>(x, h_bf, s1b);
    k_small4<<<dim3(96), 256, 0, stream>>>(W2cat, W1rm, W12t, W1bt, W1ab, W1ct,
                                           W2bt, W2ab, W2ct, s1b, Wcat, Acat, b1);
    // S23: t12 = [t1b1|u1s] @ [W2'^T|Wl2^T]^T + b2   (K=2048)
    gemm_bt<1><<<dim3(1, H_ / 128), 256, 0, stream>>>(Acat, W2cat, t12, nullptr, b2,
                                                      H_, 2048, 31, 1.0f, 1.0f);

    // --- main chain (3 e2 GEMMs; grids all >= 512 wgs -> 2 blocks/CU) ---
    // GA: h2 = h @ W12 + t12   [32768,1024] K=512 -> 128x8 = 1024 wgs
    gemm_e2<0, 0><<<dim3(1024), 512, 0, stream>>>(h_bf, W12t, nullptr, h2_bf, t12, H_, T_, 8, 3);
    // GB: q = sigma(h2 @ W1c) transposed q[B,T,N]   K=1024 -> 128x4 = 512 wgs
    gemm_e2<1, 2><<<dim3(512), 512, 0, stream>>>(h2_bf, W1ct, nullptr, q_bf, nullptr, T_, H_, 0, 2);
    // GC: out = sigma(q @ W2c) f32   [65536,1024] K=256 -> 256x8 = 2048 wgs
    gemm_e2<1, 1><<<dim3(2048), 512, 0, stream>>>(q_bf, W2ct, out, nullptr, nullptr, H_, N_, 0, 3);
}

// Round 10
// 291.562 us; speedup vs baseline: 1.8806x; 1.0026x over previous
//
#include <hip/hip_runtime.h>
#include <hip/hip_bf16.h>

#define B_ 128
#define T_ 512
#define N_ 256
#define H_ 1024

typedef unsigned short u16;
typedef __attribute__((ext_vector_type(8))) __bf16 bf16x8;
typedef __attribute__((ext_vector_type(4))) float f32x4;

__device__ __forceinline__ u16 f2bf(float f) {
    unsigned u = __float_as_uint(f);
    u = (u + 0x7FFFu + ((u >> 16) & 1u)) >> 16;
    return (u16)u;
}

__device__ __forceinline__ void g2l16(const void* g, void* l) {
    __builtin_amdgcn_global_load_lds(
        (const __attribute__((address_space(1))) void*)g,
        (__attribute__((address_space(3))) void*)l,
        16, 0, 0);
}

// ===========================================================================
// R10 "e3" engine: 256x128 tile, 8 waves of 64x64, BK=32, 3-slot LDS ring
// (3 x 24 KiB = 72 KiB) -> still 2 blocks/CU (144 <= 160 KiB).
// Counted gate vmcnt(3): prefetch 2 tiles deep (~1200+ cyc) > HBM latency.
// C[M,Nc] = act( A[M,K] @ Bt[Nc,K]^T + bias ), A/Bt bf16 row-major [*,K].
// OUT: 0 = bf16 row-major, 1 = f32 row-major, 2 = bf16 transposed q-write.
// ===========================================================================
#define ASLOT 12288u   // u16 per ring slot: A[256][32] (8192) + B[128][32] (4096)

#define GATE(N) { asm volatile("s_waitcnt vmcnt(" #N ")" ::: "memory"); \
                  __builtin_amdgcn_s_barrier(); }
#define LD4(dst, base) { _Pragma("unroll") for (int i_ = 0; i_ < 4; ++i_) \
    dst[i_] = *(const bf16x8*)(L + (base) + i_ * 512); }
#define STAGE(tile) { const u16* a_ = gA + (size_t)(tile) * 32; \
    const u16* b_ = gB + (size_t)(tile) * 32; \
    const unsigned s_ = (unsigned)(((tile) % 3) * ASLOT); \
    g2l16(a_, dA0 + s_);  g2l16(a_ + jstr, dA0 + s_ + 4096); \
    g2l16(b_, dB0 + s_); }
#define BODY(t) { \
    const unsigned sl = (unsigned)(((t) % 3) * ASLOT); \
    bf16x8 ra[4], rb[4]; \
    LD4(ra, sl + aoff); \
    LD4(rb, sl + boff); \
    if ((t) + 2 < nt) STAGE((t) + 2); \
    __builtin_amdgcn_s_setprio(1); \
    _Pragma("unroll") for (int mi_ = 0; mi_ < 4; ++mi_) \
    _Pragma("unroll") for (int ni_ = 0; ni_ < 4; ++ni_) \
        acc[mi_][ni_] = __builtin_amdgcn_mfma_f32_16x16x32_bf16( \
            ra[mi_], rb[ni_], acc[mi_][ni_], 0, 0, 0); \
    __builtin_amdgcn_s_setprio(0); }

template<int ACT, int OUT>
__global__ __launch_bounds__(512, 2) void gemm_e3(
    const u16* __restrict__ A, const u16* __restrict__ Bt,
    float* __restrict__ Cf, u16* __restrict__ Cb,
    const float* __restrict__ bias,
    int Nc, int K, int bshift, int gysh)
{
    __shared__ u16 L[36864];   // 72 KiB
    const int tid = threadIdx.x;
    const int wave = tid >> 6, lane = tid & 63;
    const int l16 = lane & 15, lh = lane >> 4;
    const int wm = wave >> 1, wn = wave & 1;   // 4x2 wave grid, 64x64 each

    // bijective XCD swizzle (all grids are multiples of 8)
    const int qq = (int)gridDim.x >> 3;
    const int orig = (int)blockIdx.x;
    const int wg = (orig & 7) * qq + (orig >> 3);
    const int by = wg & ((1 << gysh) - 1), bx = wg >> gysh;
    const size_t m0 = (size_t)bx * 256, n0 = (size_t)by * 128;

    // read-side swizzled fragment offsets (16B slot ^= (row>>1)&3)
    const int sx8 = (lh ^ ((l16 >> 1) & 3)) * 8;
    const unsigned aoff = (unsigned)(wm * 2048 + l16 * 32 + sx8);
    const unsigned boff = (unsigned)(8192 + wn * 2048 + l16 * 32 + sx8);

    // staging: thread row tid>>2 (A also +128), 16B chunk tid&3, pre-swz src
    const int srow = tid >> 2;
    const int sslot = (tid & 3) ^ ((srow >> 1) & 3);
    const size_t jstr = (size_t)128 * K;
    const u16* gA = A + (m0 + srow) * (size_t)K + sslot * 8;
    const u16* gB = Bt + (n0 + srow) * (size_t)K + sslot * 8;
    u16* const dA0 = L + (unsigned)(wave * 512);
    u16* const dB0 = L + 8192 + (unsigned)(wave * 512);

    f32x4 acc[4][4] = {};
    const int nt = K >> 5;   // >= 8 for all uses

    STAGE(0); STAGE(1);      // 6 loads in flight
    for (int t = 0; t < nt - 1; ++t) {
        GATE(3);             // tile t landed; tile t+1's 3 stay in flight
        BODY(t);
    }
    GATE(0);                 // last tile
    { const int t = nt - 1; BODY(t); }

    // epilogue: C/D layout col = lane&15, row = (lane>>4)*4 + reg
    const size_t NcS = (size_t)Nc;
#pragma unroll
    for (int mi = 0; mi < 4; ++mi) {
#pragma unroll
        for (int ni = 0; ni < 4; ++ni) {
            size_t rbase = m0 + wm * 64 + mi * 16 + lh * 4;
            size_t col   = n0 + wn * 64 + ni * 16 + l16;
            if (OUT == 2) {
                u16 e[4];
#pragma unroll
                for (int rr = 0; rr < 4; ++rr) {
                    float v = acc[mi][ni][rr];
                    v = 1.0f / (1.0f + __expf(-v));
                    e[rr] = f2bf(v);
                }
                size_t qi = ((rbase >> 8) * (size_t)T_ + col) * N_ + (rbase & 255);
                *(uint2*)(Cb + qi) = *(const uint2*)e;
            } else {
#pragma unroll
                for (int rr = 0; rr < 4; ++rr) {
                    size_t row = rbase + rr;
                    float v = acc[mi][ni][rr];
                    if (bias) v += bias[(row >> bshift) * NcS + col];
                    if (ACT) v = 1.0f / (1.0f + __expf(-v));
                    if (OUT == 1) Cf[row * NcS + col] = v;
                    else          Cb[row * NcS + col] = f2bf(v);
                }
            }
        }
    }
}

// ---------------------------------------------------------------------------
// 128x128 2-barrier GEMM body (device fn) for small GEMMs.
// ---------------------------------------------------------------------------
__device__ __forceinline__ void small_body(
    const u16* __restrict__ A, const u16* __restrict__ Bt,
    float* __restrict__ Cf, u16* __restrict__ Cb,
    const float* __restrict__ bias,
    int Nc, int K, int lda, int ldb, int outmode, int bshift,
    float kscale, float bmul, int bx, int by)
{
    __shared__ u16 lA[128 * 64];
    __shared__ u16 lB[128 * 64];
    const int tid = threadIdx.x;
    const int wave = tid >> 6, lane = tid & 63;
    const int l16 = lane & 15, lh = lane >> 4;
    const int wm = wave >> 1, wn = wave & 1;
    const long m0 = (long)bx * 128;
    const long n0 = (long)by * 128;

    f32x4 acc[4][4] = {};

    for (int k0 = 0; k0 < K; k0 += 64) {
#pragma unroll
        for (int j = 0; j < 4; ++j) {
            int c = j * 256 + tid;
            int row = c >> 3, col = (c & 7) << 3;
            g2l16(A  + (m0 + row) * (size_t)lda + k0 + col, &lA[(size_t)(j * 256 + (wave << 6)) * 8]);
            g2l16(Bt + (n0 + row) * (size_t)ldb + k0 + col, &lB[(size_t)(j * 256 + (wave << 6)) * 8]);
        }
        __syncthreads();
#pragma unroll
        for (int s = 0; s < 2; ++s) {
            bf16x8 af[4], bfr[4];
#pragma unroll
            for (int mi = 0; mi < 4; ++mi)
                af[mi] = *(const bf16x8*)&lA[((wm << 6) + (mi << 4) + l16) * 64 + s * 32 + (lh << 3)];
#pragma unroll
            for (int ni = 0; ni < 4; ++ni)
                bfr[ni] = *(const bf16x8*)&lB[((wn << 6) + (ni << 4) + l16) * 64 + s * 32 + (lh << 3)];
#pragma unroll
            for (int mi = 0; mi < 4; ++mi)
#pragma unroll
                for (int ni = 0; ni < 4; ++ni)
                    acc[mi][ni] = __builtin_amdgcn_mfma_f32_16x16x32_bf16(af[mi], bfr[ni], acc[mi][ni], 0, 0, 0);
        }
        __syncthreads();
    }

#pragma unroll
    for (int mi = 0; mi < 4; ++mi) {
#pragma unroll
        for (int ni = 0; ni < 4; ++ni) {
            long rbase = m0 + (wm << 6) + (mi << 4) + (lh << 2);
            long col   = n0 + (wn << 6) + (ni << 4) + l16;
#pragma unroll
            for (int r = 0; r < 4; ++r) {
                long row = rbase + r;
                float v = acc[mi][ni][r] * kscale;
                if (outmode == 2) {
                    v += (col < 1024 ? 1.0f : 256.0f / 255.0f) * bias[col & 1023];
                    Cb[(size_t)row * Nc + col] = f2bf(v);
                } else {
                    if (bias) v += bmul * bias[(size_t)(row >> bshift) * Nc + col];
                    if (outmode == 1) Cf[(size_t)row * Nc + col] = v;
                    else              Cb[(size_t)row * Nc + col] = f2bf(v);
                }
            }
        }
    }
}

template<int OUTF32>
__global__ __launch_bounds__(256) void gemm_bt(
    const u16* __restrict__ A, const u16* __restrict__ Bt,
    float* __restrict__ Cf, u16* __restrict__ Cb,
    const float* __restrict__ bias,
    int Nc, int K, int bshift, float kscale, float bmul)
{
    small_body(A, Bt, Cf, Cb, bias, Nc, K, K, K, OUTF32, bshift, kscale, bmul,
               blockIdx.x, blockIdx.y);
}

// Four independent small GEMMs in one launch (96 blocks)
__global__ __launch_bounds__(256) void k_small4(
    const u16* __restrict__ W2cat, const u16* __restrict__ W1rm, u16* __restrict__ W12t,
    const u16* __restrict__ W1bt, const u16* __restrict__ W1ab, u16* __restrict__ W1ct,
    const u16* __restrict__ W2bt, const u16* __restrict__ W2ab, u16* __restrict__ W2ct,
    const u16* __restrict__ s1b, const u16* __restrict__ Wcat, u16* __restrict__ Acat,
    const float* __restrict__ b1)
{
    const int bid = blockIdx.x;
    if (bid < 32) {
        small_body(W2cat, W1rm, nullptr, W12t, nullptr, 512, 1024, 2048, 1024,
                   0, 0, 1.0f, 0.0f, bid >> 2, bid & 3);
    } else if (bid < 64) {
        int r = bid - 32;
        small_body(W1bt, W1ab, nullptr, W1ct, nullptr, 1024, 1024, 1024, 1024,
                   0, 0, 1.0f, 0.0f, r >> 3, r & 7);
    } else if (bid < 80) {
        int r = bid - 64;
        small_body(W2bt, W2ab, nullptr, W2ct, nullptr, 256, 256, 256, 256,
                   0, 0, 1.0f, 0.0f, r >> 1, r & 1);
    } else {
        int r = bid - 80;
        small_body(s1b, Wcat, nullptr, Acat, b1, 2048, 512, 512, 512,
                   2, 0, 1.0f / 255.0f, 0.0f, 0, r);
    }
}

// x[B,T,N] f32 -> h[B,N,T] bf16 transpose + per-(b,t) rowsum (one x read)
__global__ __launch_bounds__(256) void k_trx_rs(
    const float* __restrict__ x, u16* __restrict__ h, u16* __restrict__ s1b)
{
    __shared__ float sm[32][257];
    const int b = blockIdx.y, t0 = blockIdx.x * 32;
    const int tid = threadIdx.x;
    const float* xb = x + ((size_t)b * T_ + t0) * N_;
#pragma unroll 8
    for (int j = 0; j < 32; ++j)
        sm[j][tid] = xb[(size_t)j * N_ + tid];
    __syncthreads();
    const int wave = tid >> 6, lane = tid & 63;
#pragma unroll
    for (int i = 0; i < 8; ++i) {
        int j = wave * 8 + i;
        float s = sm[j][lane] + sm[j][lane + 64] + sm[j][lane + 128] + sm[j][lane + 192];
#pragma unroll
        for (int o = 32; o; o >>= 1) s += __shfl_down(s, o, 64);
        if (lane == 0) s1b[(size_t)b * T_ + t0 + j] = f2bf(s);
    }
    u16 e[32];
#pragma unroll
    for (int j = 0; j < 32; ++j) e[j] = f2bf(sm[j][tid]);
    uint4* dst = (uint4*)(h + ((size_t)b * N_ + tid) * T_ + t0);
    const uint4* src = (const uint4*)e;
#pragma unroll
    for (int v = 0; v < 4; ++v) dst[v] = src[v];
}

// All weight transforms in one launch (2848 blocks of (32,8))
__global__ void k_wtr(const float* __restrict__ Wl1, const float* __restrict__ Wr1,
                      const float* __restrict__ Wl2, const float* __restrict__ Wr2,
                      const float* __restrict__ W1b, const float* __restrict__ W2b,
                      const float* __restrict__ W1a, const float* __restrict__ W2a,
                      u16* __restrict__ Wcat, u16* __restrict__ W1rm,
                      u16* __restrict__ W2cat,
                      u16* __restrict__ W1bt, u16* __restrict__ W2bt,
                      u16* __restrict__ W1ab, u16* __restrict__ W2ab)
{
    __shared__ float tl[32][33], tr[32][33];
    int bid = blockIdx.x;
    const int tx = threadIdx.x, ty = threadIdx.y;
    if (bid < 512) {
        int r0 = (bid >> 5) * 32, c0 = (bid & 31) * 32;
#pragma unroll
        for (int i = 0; i < 4; ++i) {
            int r = r0 + ty + 8 * i;
            float wl = Wl1[(size_t)r * H_ + c0 + tx];
            float wr = Wr1[(size_t)r * H_ + c0 + tx];
            tl[ty + 8 * i][tx] = wl;
            tr[ty + 8 * i][tx] = wl + wr;
            W1rm[(size_t)r * H_ + c0 + tx] = f2bf(wr - wl * (1.0f / 255.0f));
        }
        __syncthreads();
#pragma unroll
        for (int i = 0; i < 4; ++i) {
            size_t o = (size_t)(c0 + ty + 8 * i) * T_ + r0 + tx;
            Wcat[o]                     = f2bf(tl[tx][ty + 8 * i]);
            Wcat[o + (size_t)1024 * T_] = f2bf(tr[tx][ty + 8 * i]);
        }
    } else if (bid < 1536) {
        bid -= 512;
        int r0 = (bid >> 5) * 32, c0 = (bid & 31) * 32;
#pragma unroll
        for (int i = 0; i < 4; ++i) {
            int r = r0 + ty + 8 * i;
            float wl = Wl2[(size_t)r * H_ + c0 + tx];
            float wr = Wr2[(size_t)r * H_ + c0 + tx];
            tl[ty + 8 * i][tx] = wr - wl * (1.0f / 255.0f);
            tr[ty + 8 * i][tx] = wl;
        }
        __syncthreads();
#pragma unroll
        for (int i = 0; i < 4; ++i) {
            size_t o = (size_t)(c0 + ty + 8 * i) * 2048 + r0 + tx;
            W2cat[o]        = f2bf(tl[tx][ty + 8 * i]);
            W2cat[o + 1024] = f2bf(tr[tx][ty + 8 * i]);
        }
    } else if (bid < 2048) {
        bid -= 1536;
        int r0 = (bid >> 4) * 32, c0 = (bid & 15) * 32;
#pragma unroll
        for (int i = 0; i < 4; ++i)
            tl[ty + 8 * i][tx] = W1b[(size_t)(r0 + ty + 8 * i) * T_ + c0 + tx];
        __syncthreads();
#pragma unroll
        for (int i = 0; i < 4; ++i)
            W1bt[(size_t)(c0 + ty + 8 * i) * H_ + r0 + tx] = f2bf(tl[tx][ty + 8 * i]);
    } else if (bid < 2304) {
        bid -= 2048;
        int r0 = (bid >> 5) * 32, c0 = (bid & 31) * 32;
#pragma unroll
        for (int i = 0; i < 4; ++i)
            tl[ty + 8 * i][tx] = W2b[(size_t)(r0 + ty + 8 * i) * H_ + c0 + tx];
        __syncthreads();
#pragma unroll
        for (int i = 0; i < 4; ++i)
            W2bt[(size_t)(c0 + ty + 8 * i) * N_ + r0 + tx] = f2bf(tl[tx][ty + 8 * i]);
    } else {
        int i = (bid - 2304) * 256 + ty * 32 + tx;
        const int n1 = H_ * H_ / 8;
        const float* s; u16* d;
        if (i < n1) { s = W1a; d = W1ab; }
        else        { s = W2a; d = W2ab; i -= n1; }
        float4 a = ((const float4*)s)[2 * i], b = ((const float4*)s)[2 * i + 1];
        u16 e[8] = {f2bf(a.x), f2bf(a.y), f2bf(a.z), f2bf(a.w),
                    f2bf(b.x), f2bf(b.y), f2bf(b.z), f2bf(b.w)};
        ((uint4*)d)[i] = *(const uint4*)e;
    }
}

extern "C" void kernel_launch(void* const* d_in, const int* in_sizes, int n_in,
                              void* d_out, int out_size, void* d_ws, size_t ws_size,
                              hipStream_t stream)
{
    const float* x   = (const float*)d_in[0];
    const float* Wl1 = (const float*)d_in[1];
    const float* Wr1 = (const float*)d_in[2];
    const float* b1  = (const float*)d_in[3];
    const float* Wl2 = (const float*)d_in[4];
    const float* Wr2 = (const float*)d_in[5];
    const float* b2  = (const float*)d_in[6];
    const float* W1a = (const float*)d_in[7];
    const float* W1b = (const float*)d_in[8];
    const float* W2a = (const float*)d_in[9];
    const float* W2b = (const float*)d_in[10];
    float* out = (float*)d_out;

    char* ws = (char*)d_ws;
    size_t off = 0;
    auto alloc = [&](size_t bytes) -> char* {
        char* p = ws + off;
        off += (bytes + 255) & ~(size_t)255;
        return p;
    };

    const size_t BN = (size_t)B_ * N_;   // 32768
    const size_t BT = (size_t)B_ * T_;   // 65536

    u16* h_bf   = (u16*)alloc(BN * T_ * 2);              // h, later q
    u16* h2_bf  = (u16*)alloc(BN * H_ * 2);
    u16* Wcat   = (u16*)alloc((size_t)2048 * T_ * 2);    // [Wl1t ; Wlr1t]
    u16* W1rm   = (u16*)alloc((size_t)T_ * H_ * 2);
    u16* W2cat  = (u16*)alloc((size_t)H_ * 2048 * 2);    // [W2'^T | Wl2^T]
    u16* W1bt   = (u16*)alloc((size_t)T_ * H_ * 2);
    u16* W1ab   = (u16*)alloc((size_t)H_ * H_ * 2);
    u16* W1ct   = (u16*)alloc((size_t)T_ * H_ * 2);
    u16* W2bt   = (u16*)alloc((size_t)H_ * N_ * 2);
    u16* W2ab   = (u16*)alloc((size_t)N_ * N_ * 2);
    u16* W2ct   = (u16*)alloc((size_t)H_ * N_ * 2);
    u16* W12t   = (u16*)alloc((size_t)H_ * T_ * 2);
    u16* s1b    = (u16*)alloc(BT * 2);
    u16* Acat   = (u16*)alloc((size_t)B_ * 2048 * 2);    // [t1b1 | u1s]
    float* t12  = (float*)alloc((size_t)B_ * H_ * 4);

    u16* q_bf = h_bf;

    // --- prep (4 launches) ---
    k_wtr<<<dim3(2848), dim3(32, 8), 0, stream>>>(Wl1, Wr1, Wl2, Wr2, W1b, W2b, W1a, W2a,
                                                  Wcat, W1rm, W2cat, W1bt, W2bt, W1ab, W2ab);
    k_trx_rs<<<dim3(T_ / 32, B_), 256, 0, stream>>>(x, h_bf, s1b);
    k_small4<<<dim3(96), 256, 0, stream>>>(W2cat, W1rm, W12t, W1bt, W1ab, W1ct,
                                           W2bt, W2ab, W2ct, s1b, Wcat, Acat, b1);
    // S23: t12 = [t1b1|u1s] @ [W2'^T|Wl2^T]^T + b2   (K=2048)
    gemm_bt<1><<<dim3(1, H_ / 128), 256, 0, stream>>>(Acat, W2cat, t12, nullptr, b2,
                                                      H_, 2048, 31, 1.0f, 1.0f);

    // --- main chain (3 e3 GEMMs; grids all >= 512 wgs -> 2 blocks/CU) ---
    // GA: h2 = h @ W12 + t12   [32768,1024] K=512 -> 128x8 = 1024 wgs
    gemm_e3<0, 0><<<dim3(1024), 512, 0, stream>>>(h_bf, W12t, nullptr, h2_bf, t12, H_, T_, 8, 3);
    // GB: q = sigma(h2 @ W1c) transposed q[B,T,N]   K=1024 -> 128x4 = 512 wgs
    gemm_e3<1, 2><<<dim3(512), 512, 0, stream>>>(h2_bf, W1ct, nullptr, q_bf, nullptr, T_, H_, 0, 2);
    // GC: out = sigma(q @ W2c) f32   [65536,1024] K=256 -> 256x8 = 2048 wgs
    gemm_e3<1, 1><<<dim3(2048), 512, 0, stream>>>(q_bf, W2ct, out, nullptr, nullptr, H_, N_, 0, 3);
}